// Round 12
// baseline (36.943 us; speedup 1.0000x reference)
//
#include <hip/hip_runtime.h>
#include <math.h>

#define BDIM 4096
#define DDIM 128
#define EPSF 1e-12f
#define TI 128
#define TJ 64
#define NSPLIT 24
#define NSLICE (NSPLIT * 2)                 // 48: one slice per 32-col half
#define ITILES (BDIM / TI)                  // 32
#define JT 8                                // Y-tiles per split (24*8 = 192)
#define FLT_BIG 3.402823466e+38f

typedef __attribute__((ext_vector_type(8))) _Float16 f16x8;
typedef __attribute__((ext_vector_type(16))) float f32x16;

// global (per-lane addr) -> linear LDS (wave-uniform base + lane*16), 16B/lane
__device__ __forceinline__ void gload_lds16(const void* g, void* l) {
    __builtin_amdgcn_global_load_lds(
        (const __attribute__((address_space(1))) unsigned int*)(uintptr_t)g,
        (__attribute__((address_space(3))) unsigned int*)(unsigned int)(uintptr_t)l,
        16, 0, 0);
}

__device__ __forceinline__ unsigned int pack2h(float x, float y) {
    _Float16 hx = (_Float16)x, hy = (_Float16)y;
    unsigned short ux, uy;
    __builtin_memcpy(&ux, &hx, 2);
    __builtin_memcpy(&uy, &hy, 2);
    return (unsigned int)ux | ((unsigned int)uy << 16);
}

// ---------------- Kernel 0: pack to MFMA-fragment layout + norms ------------
// Xp[mat][sl(16)][row(4096)] : 16B chunk = 8 fp16 (k = sl*8..sl*8+7) of row.
__global__ __launch_bounds__(256) void prep_kernel(
    const float* __restrict__ A, const float* __restrict__ P,
    const float* __restrict__ N, uint4* __restrict__ Xp,
    float* __restrict__ a2, float* __restrict__ p2,
    float* __restrict__ n2, float* __restrict__ dpos) {
    int gid = blockIdx.x * 256 + threadIdx.x;   // 0..65535
    int sl = gid & 15;
    int row = gid >> 4;
    const float4 a0 = *(const float4*)&A[row * DDIM + sl * 8];
    const float4 a1 = *(const float4*)&A[row * DDIM + sl * 8 + 4];
    const float4 p0 = *(const float4*)&P[row * DDIM + sl * 8];
    const float4 p1 = *(const float4*)&P[row * DDIM + sl * 8 + 4];
    const float4 n0 = *(const float4*)&N[row * DDIM + sl * 8];
    const float4 n1 = *(const float4*)&N[row * DDIM + sl * 8 + 4];
    uint4 ca = {pack2h(a0.x, a0.y), pack2h(a0.z, a0.w),
                pack2h(a1.x, a1.y), pack2h(a1.z, a1.w)};
    uint4 cp = {pack2h(p0.x, p0.y), pack2h(p0.z, p0.w),
                pack2h(p1.x, p1.y), pack2h(p1.z, p1.w)};
    uint4 cn = {pack2h(n0.x, n0.y), pack2h(n0.z, n0.w),
                pack2h(n1.x, n1.y), pack2h(n1.z, n1.w)};
    Xp[(0 * 16 + sl) * BDIM + row] = ca;
    Xp[(1 * 16 + sl) * BDIM + row] = cp;
    Xp[(2 * 16 + sl) * BDIM + row] = cn;
    float sa = a0.x*a0.x + a0.y*a0.y + a0.z*a0.z + a0.w*a0.w
             + a1.x*a1.x + a1.y*a1.y + a1.z*a1.z + a1.w*a1.w;
    float sp = p0.x*p0.x + p0.y*p0.y + p0.z*p0.z + p0.w*p0.w
             + p1.x*p1.x + p1.y*p1.y + p1.z*p1.z + p1.w*p1.w;
    float sn = n0.x*n0.x + n0.y*n0.y + n0.z*n0.z + n0.w*n0.w
             + n1.x*n1.x + n1.y*n1.y + n1.z*n1.z + n1.w*n1.w;
    float d0 = a0.x-p0.x, d1 = a0.y-p0.y, d2 = a0.z-p0.z, d3 = a0.w-p0.w;
    float d4 = a1.x-p1.x, d5 = a1.y-p1.y, d6 = a1.z-p1.z, d7 = a1.w-p1.w;
    float sd = d0*d0 + d1*d1 + d2*d2 + d3*d3 + d4*d4 + d5*d5 + d6*d6 + d7*d7;
    #pragma unroll
    for (int off = 1; off < 16; off <<= 1) {
        sa += __shfl_xor(sa, off);
        sp += __shfl_xor(sp, off);
        sn += __shfl_xor(sn, off);
        sd += __shfl_xor(sd, off);
    }
    if (sl == 0) {
        a2[row] = sa;
        p2[row] = sp;
        n2[row] = sn;
        dpos[row] = sqrtf(fmaxf(sd, EPSF));
    }
}

// ---------------- Kernel 1: fp16 MFMA min of (y2/2 - dot) ----------------
// grid (32 i-tiles, 24 splits) = 768 = 3 blocks/CU (32 KB LDS). 4 waves;
// wave = 64 A-rows x 32 Y-cols (B-reuse 2). Shared double-buffered Y tile,
// counted vmcnt, 2 barriers/tile, setprio. Packed Xp layout -> all global
// loads coalesced (1 KB/instr) and LDS reads conflict-free.
__global__ __launch_bounds__(256, 2) void minsq_kernel(
    const ushort* __restrict__ Xp,
    const float* __restrict__ a2, const float* __restrict__ p2,
    const float* __restrict__ n2, float* __restrict__ partial) {
    __shared__ __align__(16) ushort Y[2][TJ * DDIM / 1];   // 2 x 16 KB

    const int tid = threadIdx.x;
    const int w = tid >> 6;
    const int lane = tid & 63;
    const int l31 = lane & 31;
    const int lhi = lane >> 5;
    const int rg = w >> 1;    // 64-row A group
    const int ch = w & 1;     // 32-col Y half
    const int iTile = blockIdx.x;
    const int split = blockIdx.y;
    const int i0 = iTile * TI;
    const int jt0 = split * JT;

    // ---- stage helper: tile jt -> buf; wave w handles slots w*4..w*4+3 ----
    // LDS layout: chunk(sl, r) at (sl*64 + r)*16B ; global src contiguous.
    // ---- prologue ----
    {
        int m = jt0 >> 6, tc = jt0 & 63;
        #pragma unroll
        for (int q = 0; q < 4; ++q) {
            int sl = w * 4 + q;
            gload_lds16(Xp + (size_t)((m * 16 + sl) * BDIM + tc * TJ + lane) * 8,
                        (ushort*)&Y[0][0] + sl * 512);
        }
    }
    // A fragments direct from packed global (coalesced, L2-resident)
    f16x8 a0[8], a1[8];
    {
        int rowA = i0 + rg * 64 + l31;
        #pragma unroll
        for (int t = 0; t < 8; ++t) {
            int sl = t * 2 + lhi;
            a0[t] = *(const f16x8*)(Xp + (size_t)(sl * BDIM + rowA) * 8);
            a1[t] = *(const f16x8*)(Xp + (size_t)(sl * BDIM + rowA + 32) * 8);
        }
    }
    // y2/2 for tile 0
    float y2buf[2];
    {
        int m = jt0 >> 6, tc = jt0 & 63;
        const float* y2g = (m == 0) ? a2 : ((m == 1) ? p2 : n2);
        y2buf[0] = 0.5f * y2g[tc * TJ + ch * 32 + l31];
    }
    asm volatile("s_waitcnt vmcnt(0)" ::: "memory");
    __builtin_amdgcn_sched_barrier(0);
    __builtin_amdgcn_s_barrier();
    __builtin_amdgcn_sched_barrier(0);

    float minv0[16], minv1[16];
    #pragma unroll
    for (int g = 0; g < 16; ++g) { minv0[g] = FLT_BIG; minv1[g] = FLT_BIG; }

    #pragma unroll
    for (int t = 0; t < JT; ++t) {
        // stage tile t+1 into other buffer + load its y2 (5 VMEM in flight)
        if (t + 1 < JT) {
            int jn = jt0 + t + 1, mn = jn >> 6, tcn = jn & 63;
            #pragma unroll
            for (int q = 0; q < 4; ++q) {
                int sl = w * 4 + q;
                gload_lds16(Xp + (size_t)((mn * 16 + sl) * BDIM + tcn * TJ + lane) * 8,
                            (ushort*)&Y[(t + 1) & 1][0] + sl * 512);
            }
            const float* y2g = (mn == 0) ? a2 : ((mn == 1) ? p2 : n2);
            y2buf[(t + 1) & 1] = 0.5f * y2g[tcn * TJ + ch * 32 + l31];
            asm volatile("s_waitcnt vmcnt(5)" ::: "memory");  // tile t staged
        } else {
            asm volatile("s_waitcnt vmcnt(0)" ::: "memory");
        }
        __builtin_amdgcn_sched_barrier(0);
        __builtin_amdgcn_s_barrier();        // tile t ready for all waves
        __builtin_amdgcn_sched_barrier(0);

        const ushort* buf = &Y[t & 1][0];
        f32x16 acc0 = {}, acc1 = {};
        __builtin_amdgcn_s_setprio(1);
        #pragma unroll
        for (int k = 0; k < 8; ++k) {
            int sl = k * 2 + lhi;
            f16x8 b = *(const f16x8*)&buf[(sl * 64 + ch * 32 + l31) * 8];
            acc0 = __builtin_amdgcn_mfma_f32_32x32x16_f16(a0[k], b, acc0, 0, 0, 0);
            acc1 = __builtin_amdgcn_mfma_f32_32x32x16_f16(a1[k], b, acc1, 0, 0, 0);
        }
        __builtin_amdgcn_s_setprio(0);

        // epilogue: running min of (y2/2 - dot); diag exclusion on A/P mats
        {
            int jt = jt0 + t, m = jt >> 6, tc = jt & 63;
            float yh = y2buf[t & 1];
            if (m < 2 && (tc >> 1) == iTile) {
                int jg = tc * TJ + ch * 32 + l31;
                #pragma unroll
                for (int g = 0; g < 16; ++g) {
                    int rloc = (g & 3) + 8 * (g >> 2) + 4 * lhi;
                    int ig0 = i0 + rg * 64 + rloc;
                    float c0 = yh - acc0[g];
                    if (ig0 == jg) c0 = FLT_BIG;
                    minv0[g] = fminf(minv0[g], c0);
                    float c1 = yh - acc1[g];
                    if (ig0 + 32 == jg) c1 = FLT_BIG;
                    minv1[g] = fminf(minv1[g], c1);
                }
            } else {
                #pragma unroll
                for (int g = 0; g < 16; ++g) {
                    minv0[g] = fminf(minv0[g], yh - acc0[g]);
                    minv1[g] = fminf(minv1[g], yh - acc1[g]);
                }
            }
        }
        __builtin_amdgcn_s_barrier();        // all reads of buf[t&1] done
    }

    // min over the 32 columns (within each 32-lane half)
    #pragma unroll
    for (int off = 1; off < 32; off <<= 1) {
        #pragma unroll
        for (int g = 0; g < 16; ++g) {
            minv0[g] = fminf(minv0[g], __shfl_xor(minv0[g], off));
            minv1[g] = fminf(minv1[g], __shfl_xor(minv1[g], off));
        }
    }
    if (l31 == 0) {
        int slice = split * 2 + ch;
        #pragma unroll
        for (int g = 0; g < 16; ++g) {
            int rloc = (g & 3) + 8 * (g >> 2) + 4 * lhi;
            int ig = i0 + rg * 64 + rloc;
            partial[(size_t)ig * NSLICE + slice] = minv0[g];
            partial[(size_t)(ig + 32) * NSLICE + slice] = minv1[g];
        }
    }
}

// ---------------- Kernel 2a: per-row loss, 16-block partial sums ------------
__global__ __launch_bounds__(256) void lossA_kernel(
    const float* __restrict__ partial, const float* __restrict__ a2,
    const float* __restrict__ dpos, float* __restrict__ bsum) {
    __shared__ float red[4];
    int i = blockIdx.x * 256 + threadIdx.x;
    const float4* pr = (const float4*)&partial[(size_t)i * NSLICE];
    float mv = FLT_BIG;
    #pragma unroll
    for (int q = 0; q < NSLICE / 4; ++q) {
        float4 v = pr[q];
        mv = fminf(mv, fminf(fminf(v.x, v.y), fminf(v.z, v.w)));
    }
    float h2 = a2[i] + 2.0f * mv;
    float hardest = sqrtf(fmaxf(h2, EPSF));
    float x = dpos[i] - hardest;
    float sum = fmaxf(x, 0.f) + log1pf(expf(-fabsf(x)));
    #pragma unroll
    for (int off = 32; off; off >>= 1) sum += __shfl_down(sum, off);
    if ((threadIdx.x & 63) == 0) red[threadIdx.x >> 6] = sum;
    __syncthreads();
    if (threadIdx.x == 0)
        bsum[blockIdx.x] = red[0] + red[1] + red[2] + red[3];
}

// ---------------- Kernel 2b: final scalar ----------------
__global__ void lossB_kernel(const float* __restrict__ bsum,
                             float* __restrict__ out) {
    float v = (threadIdx.x < 16) ? bsum[threadIdx.x] : 0.f;
    #pragma unroll
    for (int off = 32; off; off >>= 1) v += __shfl_down(v, off);
    if (threadIdx.x == 0) out[0] = v * (1.0f / BDIM);
}

extern "C" void kernel_launch(void* const* d_in, const int* in_sizes, int n_in,
                              void* d_out, int out_size, void* d_ws, size_t ws_size,
                              hipStream_t stream) {
    const float* A = (const float*)d_in[0];
    const float* P = (const float*)d_in[1];
    const float* N = (const float*)d_in[2];

    float* ws = (float*)d_ws;
    float* a2 = ws;                          // 4096
    float* p2 = ws + BDIM;                   // 4096
    float* n2 = ws + 2 * BDIM;               // 4096
    float* dpos = ws + 3 * BDIM;             // 4096
    float* bsum = ws + 4 * BDIM;             // 64 (16 used)
    float* partial = ws + 4 * BDIM + 64;     // BDIM * NSLICE (row-major)
    uint4* Xp = (uint4*)(partial + (size_t)BDIM * NSLICE);  // 3 * 16*4096 chunks

    prep_kernel<<<256, 256, 0, stream>>>(A, P, N, Xp, a2, p2, n2, dpos);
    dim3 grid2(ITILES, NSPLIT);
    minsq_kernel<<<grid2, 256, 0, stream>>>((const ushort*)Xp, a2, p2, n2, partial);
    lossA_kernel<<<16, 256, 0, stream>>>(partial, a2, dpos, bsum);
    lossB_kernel<<<1, 64, 0, stream>>>(bsum, (float*)d_out);
}